// Round 4
// baseline (202.623 us; speedup 1.0000x reference)
//
#include <hip/hip_runtime.h>
#include <math.h>

// BioTripletLoss: B=16384 rows, D=1024 fp32.
// pos_dist[i] = ||h[i]+r[i]-t[i]||, neg_dist[i] = ||h[i]+r[i]-t[neg_idx[i]]||
// dissim (rel==1): relu(0.6 - pos) + 0.5*exp(-pos)
// sim:             relu(pos - neg + 0.3) + 0.3*relu(0.1 - pos)
// out = mean(per_sample)
//
// R11: 4 rows per wave. Post-mortems R7-R10: time (~78us) invariant to
// load path (LDS-DMA vs VGPR), occupancy (30 vs 54%), residency (L3 vs
// HBM), and atomic-vs-store -> delivered-to-CU BW stuck at 3.5 TB/s
// (5.7 B/cy/CU), 70% of the best read-dominated rate on this chip
// (RMSNorm 4.89 TB/s). Wave residency math (occ 54%, 16384 waves, 76us)
// gives 48k cycles/wave for 16KB: waves die young and spend their lives
// queued. What all prior variants share vs a pure streaming kernel:
// 4KB streams, a dependent gather head per wave, and a reduce tail per
// 16KB. Fix: each wave owns 4 CONSECUTIVE rows -> 16KB contiguous per
// stream, one int4 neg/rel prefetch, reduce tail amortized 4x, and
// cross-row load/compute software-pipelining (unrolled row loop, no
// sched_barrier, 128-VGPR budget).

#define BDIM 16384
#define DDIM 1024
#define NBLK (BDIM / 16)   // 4 waves/block x 4 rows/wave = 16 rows/block

typedef float vfloat4 __attribute__((ext_vector_type(4)));
typedef int   vint4   __attribute__((ext_vector_type(4)));

__global__ void zero_out_kernel(float* __restrict__ out) { out[0] = 0.0f; }

template <int USE_WS>
__global__ __launch_bounds__(256, 4) void triplet_partial_kernel(
    const float* __restrict__ h, const float* __restrict__ t,
    const float* __restrict__ r, const int* __restrict__ rel,
    const int* __restrict__ neg, float* __restrict__ sink)
{
    __shared__ float sm[4];

    const int wave = threadIdx.x >> 6;
    const int lane = threadIdx.x & 63;
    const int r0   = ((blockIdx.x << 2) + wave) << 2;   // 4 consecutive rows

    // dependency head paid once: neg/rel for all 4 rows (aligned int4)
    const vint4 nidx = *(const vint4*)(neg + r0);
    const vint4 rli  = *(const vint4*)(rel + r0);

    float psum[4], nsum[4];
    float loss[4];

#pragma unroll
    for (int j = 0; j < 4; ++j) {
        const int row = r0 + j;
        const vfloat4* hb = (const vfloat4*)(h + (size_t)row * DDIM) + lane;
        const vfloat4* rb = (const vfloat4*)(r + (size_t)row * DDIM) + lane;
        const vfloat4* tb = (const vfloat4*)(t + (size_t)row * DDIM) + lane;
        // dissim rows never use neg_dist: alias gather to own t row
        const vfloat4* nb = (rli[j] == 1) ? tb
                           : (const vfloat4*)(t + (size_t)nidx[j] * DDIM) + lane;

        vfloat4 hv[4], rv[4], tv[4], nv[4];
#pragma unroll
        for (int c = 0; c < 4; ++c) {
            hv[c] = hb[c << 6];
            rv[c] = rb[c << 6];
            tv[c] = tb[c << 6];
            nv[c] = nb[c << 6];
        }

        float ps = 0.0f, ns = 0.0f;
#pragma unroll
        for (int c = 0; c < 4; ++c) {
            vfloat4 a = hv[c] + rv[c];
            vfloat4 d = a - tv[c];
            vfloat4 e = a - nv[c];
            ps += d.x * d.x + d.y * d.y + d.z * d.z + d.w * d.w;
            ns += e.x * e.x + e.y * e.y + e.z * e.z + e.w * e.w;
        }
        psum[j] = ps;
        nsum[j] = ns;
    }

    // wave-64 butterfly reduction, 8 accumulators (tail amortized 4 rows)
#pragma unroll
    for (int off = 32; off > 0; off >>= 1) {
#pragma unroll
        for (int j = 0; j < 4; ++j) {
            psum[j] += __shfl_down(psum[j], off, 64);
            nsum[j] += __shfl_down(nsum[j], off, 64);
        }
    }

    if (lane == 0) {
#pragma unroll
        for (int j = 0; j < 4; ++j) {
            float pos  = sqrtf(psum[j]);
            float negd = sqrtf(nsum[j]);
            if (rli[j] == 1)
                loss[j] = fmaxf(0.6f - pos, 0.0f) + 0.5f * expf(-pos);
            else
                loss[j] = fmaxf(pos - negd + 0.3f, 0.0f)
                        + 0.3f * fmaxf(0.1f - pos, 0.0f);
        }
        sm[wave] = loss[0] + loss[1] + loss[2] + loss[3];
    }
    __syncthreads();
    if (threadIdx.x == 0) {
        float blk = sm[0] + sm[1] + sm[2] + sm[3];
        if (USE_WS) {
            sink[blockIdx.x] = blk;                       // partial
        } else {
            atomicAdd(sink, blk * (1.0f / (float)BDIM));  // fallback
        }
    }
}

// 1 block x 256 threads: sum NBLK=1024 partials, write mean to out.
__global__ __launch_bounds__(256) void reduce_partials_kernel(
    const float* __restrict__ ws, float* __restrict__ out)
{
    __shared__ float sm[4];
    const int tid  = threadIdx.x;
    const int wave = tid >> 6;
    const int lane = tid & 63;

    vfloat4 v = ((const vfloat4*)ws)[tid];   // 4 floats per thread
    float s = v.x + v.y + v.z + v.w;

#pragma unroll
    for (int off = 32; off > 0; off >>= 1)
        s += __shfl_down(s, off, 64);

    if (lane == 0) sm[wave] = s;
    __syncthreads();
    if (tid == 0)
        out[0] = (sm[0] + sm[1] + sm[2] + sm[3]) * (1.0f / (float)BDIM);
}

extern "C" void kernel_launch(void* const* d_in, const int* in_sizes, int n_in,
                              void* d_out, int out_size, void* d_ws, size_t ws_size,
                              hipStream_t stream) {
    const float* h = (const float*)d_in[0];
    const float* t = (const float*)d_in[1];
    const float* r = (const float*)d_in[2];
    const int* rel = (const int*)d_in[3];
    const int* neg = (const int*)d_in[4];
    float* out = (float*)d_out;
    float* ws  = (float*)d_ws;   // need NBLK floats = 4 KB

    if (ws != nullptr && ws_size >= NBLK * sizeof(float)) {
        triplet_partial_kernel<1><<<NBLK, 256, 0, stream>>>(h, t, r, rel, neg, ws);
        reduce_partials_kernel<<<1, 256, 0, stream>>>(ws, out);
    } else {
        zero_out_kernel<<<1, 1, 0, stream>>>(out);
        triplet_partial_kernel<0><<<NBLK, 256, 0, stream>>>(h, t, r, rel, neg, out);
    }
}